// Round 12
// baseline (284.072 us; speedup 1.0000x reference)
//
#include <hip/hip_runtime.h>
#include <hip/hip_fp16.h>

constexpr int NN  = 100000;
constexpr int NE  = 1600000;
constexpr int TOT = NE + NN;

constexpr int NBUK    = (NN + 255) / 256;   // 391 buckets of 256 nodes (by dst>>8)
constexpr int EBLOCKS = 512;                // blocks for hist/scatter passes
constexpr int EPB     = NE / EBLOCKS;       // 3125 edges per block (exact)

typedef _Float16 f16x8 __attribute__((ext_vector_type(8)));
typedef _Float16 f16x4 __attribute__((ext_vector_type(4)));
typedef float    f32x4 __attribute__((ext_vector_type(4)));

// ---------- fp16 helpers ----------
__device__ inline float2 h2f2(unsigned int u) {
  __half2 h = __builtin_bit_cast(__half2, u);
  return __half22float2(h);
}
__device__ inline unsigned int f2h2(float a, float b) {
  __half2 h = __floats2half2_rn(a, b);
  return __builtin_bit_cast(unsigned int, h);
}

// ---------- inline edge_index dtype probe (per block) ----------
__device__ inline int block_is64(const unsigned int* ei) {
  unsigned int w = ei[threadIdx.x * 2 + 1];
  int nz = __syncthreads_count(w != 0u);
  return nz == 0;
}

__device__ inline int load_idx(const void* ei, long long i, int is64) {
  return is64 ? (int)((const long long*)ei)[i] : ((const int*)ei)[i];
}

// ---------- bucketed CSR build (no global atomics) ----------

__global__ __launch_bounds__(256) void k_hist(const void* __restrict__ ei, int* __restrict__ hist_g) {
  __shared__ int h[NBUK];
  int is64 = block_is64((const unsigned int*)ei);
  for (int i = threadIdx.x; i < NBUK; i += 256) h[i] = 0;
  __syncthreads();
  int e0 = blockIdx.x * EPB;
  for (int e = e0 + threadIdx.x; e < e0 + EPB; e += 256) {
    int d = load_idx(ei, (long long)NE + e, is64);
    atomicAdd(&h[d >> 8], 1);
  }
  __syncthreads();
  for (int i = threadIdx.x; i < NBUK; i += 256)
    hist_g[i * EBLOCKS + blockIdx.x] = h[i];
}

__global__ __launch_bounds__(512) void k_scan_hist(int* __restrict__ hist_g, int* __restrict__ bucket_total) {
  __shared__ int s[EBLOCKS];
  int b = blockIdx.x, t = threadIdx.x;
  int v = hist_g[b * EBLOCKS + t];
  s[t] = v;
  __syncthreads();
  for (int off = 1; off < EBLOCKS; off <<= 1) {
    int u = (t >= off) ? s[t - off] : 0;
    __syncthreads();
    s[t] += u;
    __syncthreads();
  }
  hist_g[b * EBLOCKS + t] = s[t] - v;
  if (t == EBLOCKS - 1) bucket_total[b] = s[t];
}

__global__ __launch_bounds__(512) void k_scan_buckets(const int* __restrict__ bucket_total,
                                                      int* __restrict__ edge_base, int* __restrict__ row_start) {
  __shared__ int s[512];
  int t = threadIdx.x;
  int v = (t < NBUK) ? bucket_total[t] : 0;
  s[t] = v;
  __syncthreads();
  for (int off = 1; off < 512; off <<= 1) {
    int u = (t >= off) ? s[t - off] : 0;
    __syncthreads();
    s[t] += u;
    __syncthreads();
  }
  if (t <= NBUK) edge_base[t] = s[t] - v;
  if (t == 0) row_start[NN] = TOT;
}

// rec packed: (src << 8) | (dst & 255)  -- src < 2^17 fits in 24 bits.
__global__ __launch_bounds__(256) void k_scatter(const void* __restrict__ ei,
                                                 const int* __restrict__ hist_g, const int* __restrict__ edge_base,
                                                 int* __restrict__ rec) {
  __shared__ int cur[NBUK];
  int is64 = block_is64((const unsigned int*)ei);
  for (int i = threadIdx.x; i < NBUK; i += 256)
    cur[i] = edge_base[i] + hist_g[i * EBLOCKS + blockIdx.x];
  __syncthreads();
  int e0 = blockIdx.x * EPB;
  for (int e = e0 + threadIdx.x; e < e0 + EPB; e += 256) {
    int sA = load_idx(ei, e, is64);
    int d  = load_idx(ei, (long long)NE + e, is64);
    int p = atomicAdd(&cur[d >> 8], 1);
    rec[p] = (sA << 8) | (d & 255);
  }
}

__global__ __launch_bounds__(256) void k_bucket_csr(const int* __restrict__ rec, const int* __restrict__ edge_base,
                                                    int* __restrict__ row_start, float* __restrict__ dinv,
                                                    int* __restrict__ csr_src) {
  __shared__ int cnt[256];
  __shared__ int s[256];
  int b = blockIdx.x, t = threadIdx.x;
  int node = b * 256 + t;
  cnt[t] = 0;
  __syncthreads();
  int j0 = edge_base[b], j1 = edge_base[b + 1];
  for (int j = j0 + t; j < j1; j += 256)
    atomicAdd(&cnt[rec[j] & 255], 1);
  __syncthreads();
  int c = (node < NN) ? cnt[t] + 1 : 0;  // +1 self-loop
  s[t] = c;
  __syncthreads();
  for (int off = 1; off < 256; off <<= 1) {
    int u = (t >= off) ? s[t - off] : 0;
    __syncthreads();
    s[t] += u;
    __syncthreads();
  }
  int csr_b = j0 + b * 256;
  int start = csr_b + s[t] - c;
  if (node < NN) {
    row_start[node] = start;
    dinv[node] = rsqrtf((float)c);
    csr_src[start] = node;              // self-loop in slot 0
  }
  __syncthreads();
  cnt[t] = start + 1;                   // reuse as cursor
  __syncthreads();
  for (int j = j0 + t; j < j1; j += 256) {
    int r = rec[j];
    int p = atomicAdd(&cnt[r & 255], 1);
    csr_src[p] = r >> 8;
  }
}

// ---------- MFMA fp16 GEMM: Y[r] = dinv[r] * (X[r] @ W), Y fp16 ----------
// X: [N,128] fp32; W: [128,OUTC] fp32. 64 rows/block, 4 waves, mfma_f32_16x16x32_f16.
template<int OUTC>
__global__ __launch_bounds__(256) void k_gemm_mfma(const float* __restrict__ X,
                                                   const float* __restrict__ W,
                                                   const float* __restrict__ dinv,
                                                   unsigned short* __restrict__ Y) {
  constexpr int NT = OUTC / 16;
  constexpr int PS = 136;              // Wt k-stride (halves)
  constexpr int SS = OUTC + 8;         // out-stage row stride (halves)
  constexpr int WT_H = OUTC * PS;
  constexpr int ST_H = 64 * SS;
  constexpr int SM_H = WT_H > ST_H ? WT_H : ST_H;
  __shared__ _Float16 smem[SM_H];

  const int tid  = threadIdx.x;
  const int lane = tid & 63;
  const int wv   = tid >> 6;
  const int row0 = blockIdx.x * 64;
  const int l15  = lane & 15;
  const int kg   = lane >> 4;

  // stage W^T with k-contiguous f16x4 writes (coalesced global, ~no LDS conflicts)
  {
    int c  = tid & (OUTC - 1);
    int k4 = tid / OUTC;               // 0..(256/OUTC - 1)
    for (int kk = k4; kk < 32; kk += 256 / OUTC) {
      int k = kk * 4;
      f16x4 w;
      w[0] = (_Float16)W[(k + 0) * OUTC + c];
      w[1] = (_Float16)W[(k + 1) * OUTC + c];
      w[2] = (_Float16)W[(k + 2) * OUTC + c];
      w[3] = (_Float16)W[(k + 3) * OUTC + c];
      *(f16x4*)&smem[c * PS + k] = w;
    }
  }
  __syncthreads();

  int arow = row0 + wv * 16 + l15;
  int rr_g = arow < NN ? arow : NN - 1;

  f32x4 acc[NT];
  #pragma unroll
  for (int n = 0; n < NT; n++) acc[n] = (f32x4){0.f, 0.f, 0.f, 0.f};

  #pragma unroll
  for (int kb = 0; kb < 4; kb++) {
    int k0 = kb * 32 + kg * 8;
    f16x8 a;
    float4 v0 = *(const float4*)&X[(size_t)rr_g * 128 + k0];
    float4 v1 = *(const float4*)&X[(size_t)rr_g * 128 + k0 + 4];
    a[0] = (_Float16)v0.x; a[1] = (_Float16)v0.y; a[2] = (_Float16)v0.z; a[3] = (_Float16)v0.w;
    a[4] = (_Float16)v1.x; a[5] = (_Float16)v1.y; a[6] = (_Float16)v1.z; a[7] = (_Float16)v1.w;
    #pragma unroll
    for (int n = 0; n < NT; n++) {
      f16x8 b = *(const f16x8*)&smem[(n * 16 + l15) * PS + k0];
      acc[n] = __builtin_amdgcn_mfma_f32_16x16x32_f16(a, b, acc[n], 0, 0, 0);
    }
  }
  __syncthreads();

  int rb = wv * 16 + kg * 4;
  float dv[4];
  #pragma unroll
  for (int q = 0; q < 4; q++) {
    int gr = row0 + rb + q;
    dv[q] = dinv[gr < NN ? gr : NN - 1];
  }
  #pragma unroll
  for (int n = 0; n < NT; n++)
    #pragma unroll
    for (int q = 0; q < 4; q++)
      smem[(rb + q) * SS + n * 16 + l15] = (_Float16)(acc[n][q] * dv[q]);
  __syncthreads();

  constexpr int SEGS = OUTC / 8;
  for (int u = tid; u < 64 * SEGS; u += 256) {
    int rr = u / SEGS, sg = u % SEGS;
    int gr = row0 + rr;
    if (gr < NN) {
      uint4 v = *(const uint4*)&smem[rr * SS + sg * 8];
      *(uint4*)&Y[(size_t)gr * OUTC + sg * 8] = v;
    }
  }
}

// ---------- fused agg1 + gemm2: Y = dinv * (relu(dinv*Σ h'[s] + b1) @ W2), fp16 ----------
// 64 nodes/block: W2 staged once per 64 nodes; gather in 4 sequential 16-node groups.
__global__ __launch_bounds__(256) void k_agg_gemm(const unsigned short* __restrict__ h,
                                                  const float* __restrict__ dinv,
                                                  const int* __restrict__ row_start,
                                                  const int* __restrict__ csr_src,
                                                  const float* __restrict__ bias,
                                                  const float* __restrict__ W,   // W2 [128,64] fp32
                                                  unsigned short* __restrict__ Y) {
  constexpr int PS = 136;   // Wt k-stride (halves)
  constexpr int AS = 136;   // At k-stride (halves)
  constexpr int OS = 72;    // out-stage row stride (halves)
  __shared__ _Float16 Wt[64 * PS];   // 17 KB
  __shared__ _Float16 At[64 * AS];   // 17 KB; reused as out-stage (64*OS < 64*AS)

  const int tid  = threadIdx.x;
  const int row0 = blockIdx.x * 64;

  // stage W2^T with k-contiguous f16x4 writes
  {
    int c  = tid & 63;
    int k4 = tid >> 6;                 // 0..3
    for (int kk = k4; kk < 32; kk += 4) {
      int k = kk * 4;
      f16x4 w;
      w[0] = (_Float16)W[(k + 0) * 64 + c];
      w[1] = (_Float16)W[(k + 1) * 64 + c];
      w[2] = (_Float16)W[(k + 2) * 64 + c];
      w[3] = (_Float16)W[(k + 3) * 64 + c];
      *(f16x4*)&Wt[c * PS + k] = w;
    }
  }

  // gather phase: 16 lanes per node, 4 sequential groups of 16 nodes
  const int ln  = tid & 15;
  const int lno = tid >> 4;            // 0..15
  #pragma unroll
  for (int g = 0; g < 4; g++) {
    int lnode = g * 16 + lno;
    int node  = row0 + lnode;
    int nc    = node < NN ? node : NN - 1;
    int j0 = row_start[nc], j1 = row_start[nc + 1];
    float acc[8] = {};
    #pragma unroll 2
    for (int j = j0; j < j1; j++) {
      int s = csr_src[j];
      uint4 v = *(const uint4*)&h[(size_t)s * 128 + ln * 8];
      float2 f;
      f = h2f2(v.x); acc[0] += f.x; acc[1] += f.y;
      f = h2f2(v.y); acc[2] += f.x; acc[3] += f.y;
      f = h2f2(v.z); acc[4] += f.x; acc[5] += f.y;
      f = h2f2(v.w); acc[6] += f.x; acc[7] += f.y;
    }
    float dn = dinv[nc];
    float o[8];
    #pragma unroll
    for (int t = 0; t < 8; t++) {
      o[t] = fmaf(dn, acc[t], bias[ln * 8 + t]);
      o[t] = fmaxf(o[t], 0.f);                   // relu (layer 1)
    }
    uint4 pk;
    pk.x = f2h2(o[0], o[1]);
    pk.y = f2h2(o[2], o[3]);
    pk.z = f2h2(o[4], o[5]);
    pk.w = f2h2(o[6], o[7]);
    *(uint4*)&At[lnode * AS + ln * 8] = pk;      // one 16B write per node-slice
  }
  __syncthreads();

  // MFMA: wave wv does output col-tile [wv*16,+16) over 4 row-tiles
  const int lane = tid & 63;
  const int wv   = tid >> 6;
  const int l15  = lane & 15;
  const int kg   = lane >> 4;
  f32x4 dacc[4];
  #pragma unroll
  for (int m = 0; m < 4; m++) dacc[m] = (f32x4){0.f, 0.f, 0.f, 0.f};
  #pragma unroll
  for (int kb = 0; kb < 4; kb++) {
    int k0 = kb * 32 + kg * 8;
    f16x8 b = *(const f16x8*)&Wt[(wv * 16 + l15) * PS + k0];
    #pragma unroll
    for (int m = 0; m < 4; m++) {
      f16x8 a = *(const f16x8*)&At[(m * 16 + l15) * AS + k0];
      dacc[m] = __builtin_amdgcn_mfma_f32_16x16x32_f16(a, b, dacc[m], 0, 0, 0);
    }
  }
  __syncthreads();   // done reading At; reuse as out-stage

  #pragma unroll
  for (int m = 0; m < 4; m++)
    #pragma unroll
    for (int q = 0; q < 4; q++) {
      int lr = m * 16 + kg * 4 + q;              // D row = local node
      int gr = row0 + lr;
      float dv = dinv[gr < NN ? gr : NN - 1];
      At[lr * OS + wv * 16 + l15] = (_Float16)(dacc[m][q] * dv);
    }
  __syncthreads();

  for (int u = tid; u < 64 * 8; u += 256) {      // 64 rows x 8 uint4 segs
    int rr = u >> 3, sg = u & 7;
    int gr = row0 + rr;
    if (gr < NN) {
      uint4 v = *(const uint4*)&At[rr * OS + sg * 8];
      *(uint4*)&Y[(size_t)gr * 64 + sg * 8] = v;
    }
  }
}

// ---------- final aggregation: out[n] = dinv[n] * Σ hL2[s] + b2 (fp32 out) ----------
__global__ __launch_bounds__(256) void k_agg_final(const unsigned short* __restrict__ h,
                                                   const float* __restrict__ dinv,
                                                   const int* __restrict__ row_start,
                                                   const int* __restrict__ csr_src,
                                                   const float* __restrict__ bias,
                                                   float* __restrict__ out) {
  constexpr int LPN = 8;            // 64 feats / 8 per lane
  int node = blockIdx.x * 32 + threadIdx.x / LPN;
  int lane = threadIdx.x % LPN;
  if (node >= NN) return;
  int j0 = row_start[node], j1 = row_start[node + 1];
  float acc[8] = {};
  #pragma unroll 2
  for (int j = j0; j < j1; j++) {
    int s = csr_src[j];
    uint4 v = *(const uint4*)&h[(size_t)s * 64 + lane * 8];
    float2 f;
    f = h2f2(v.x); acc[0] += f.x; acc[1] += f.y;
    f = h2f2(v.y); acc[2] += f.x; acc[3] += f.y;
    f = h2f2(v.z); acc[4] += f.x; acc[5] += f.y;
    f = h2f2(v.w); acc[6] += f.x; acc[7] += f.y;
  }
  float dn = dinv[node];
  float o[8];
  #pragma unroll
  for (int t = 0; t < 8; t++) o[t] = fmaf(dn, acc[t], bias[lane * 8 + t]);
  *(float4*)&out[(size_t)node * 64 + lane * 8]     = make_float4(o[0], o[1], o[2], o[3]);
  *(float4*)&out[(size_t)node * 64 + lane * 8 + 4] = make_float4(o[4], o[5], o[6], o[7]);
}

// ---------- launch ----------
extern "C" void kernel_launch(void* const* d_in, const int* in_sizes, int n_in,
                              void* d_out, int out_size, void* d_ws, size_t ws_size,
                              hipStream_t stream) {
  const float* x  = (const float*)d_in[0];
  const void*  ei = d_in[1];
  const float* W1 = (const float*)d_in[2];
  const float* b1 = (const float*)d_in[3];
  const float* W2 = (const float*)d_in[4];
  const float* b2 = (const float*)d_in[5];
  float* out = (float*)d_out;

  char* ws = (char*)d_ws;
  size_t off = 0;
  auto wsalloc = [&](size_t bytes) -> void* {
    void* p = ws + off;
    off += (bytes + 255) & ~(size_t)255;
    return p;
  };
  int*            row_start    = (int*)   wsalloc((NN + 1) * sizeof(int));
  int*            hist_g       = (int*)   wsalloc((size_t)NBUK * EBLOCKS * sizeof(int));
  int*            bucket_total = (int*)   wsalloc(NBUK * sizeof(int));
  int*            edge_base    = (int*)   wsalloc((NBUK + 1) * sizeof(int));
  float*          dinv         = (float*) wsalloc(NN * sizeof(float));
  int*            rec          = (int*)   wsalloc((size_t)NE * sizeof(int));
  int*            csr_src      = (int*)   wsalloc((size_t)TOT * sizeof(int));
  unsigned short* h1           = (unsigned short*)wsalloc((size_t)NN * 128 * sizeof(unsigned short));
  unsigned short* hL2          = (unsigned short*)wsalloc((size_t)NN * 64 * sizeof(unsigned short));

  k_hist<<<EBLOCKS, 256, 0, stream>>>(ei, hist_g);
  k_scan_hist<<<NBUK, EBLOCKS, 0, stream>>>(hist_g, bucket_total);
  k_scan_buckets<<<1, 512, 0, stream>>>(bucket_total, edge_base, row_start);
  k_scatter<<<EBLOCKS, 256, 0, stream>>>(ei, hist_g, edge_base, rec);
  k_bucket_csr<<<NBUK, 256, 0, stream>>>(rec, edge_base, row_start, dinv, csr_src);

  k_gemm_mfma<128><<<(NN + 63) / 64, 256, 0, stream>>>(x, W1, dinv, h1);
  k_agg_gemm<<<(NN + 63) / 64, 256, 0, stream>>>(h1, dinv, row_start, csr_src, b1, W2, hL2);
  k_agg_final<<<(NN + 31) / 32, 256, 0, stream>>>(hL2, dinv, row_start, csr_src, b2, out);
}